// Round 9
// baseline (190.792 us; speedup 1.0000x reference)
//
#include <hip/hip_runtime.h>
#include <hip/hip_bf16.h>

typedef __attribute__((ext_vector_type(8))) short bf16x8;
typedef __attribute__((ext_vector_type(4))) float f32x4;
typedef __attribute__((ext_vector_type(4))) int i32x4;
typedef __attribute__((ext_vector_type(4))) unsigned short u16x4;
typedef __attribute__((ext_vector_type(2))) unsigned ui2;
typedef __attribute__((ext_vector_type(4))) float fl4;

struct __attribute__((packed)) u16x4u { u16x4 v; };   // unaligned vector store

__device__ __forceinline__ f32x4 mfma16(bf16x8 a, bf16x8 b, f32x4 c) {
    return __builtin_amdgcn_mfma_f32_16x16x32_bf16(a, b, c, 0, 0, 0);
}

__device__ __forceinline__ unsigned short f2b(float f) {
    unsigned u = __float_as_uint(f);
    unsigned r = (u + 0x7FFF + ((u >> 16) & 1)) >> 16;
    return (unsigned short)r;
}

__device__ __forceinline__ int bsearch_off(const int* s_off, int m) {
    int lo = 0, hi = 63;
    while (lo < hi) {
        int mid = (lo + hi + 1) >> 1;
        if (s_off[mid] <= m) lo = mid; else hi = mid - 1;
    }
    return lo;
}

// async global->LDS, 16B per lane; lds base must be wave-uniform (HW adds lane*16)
__device__ __forceinline__ void gld_lds16(const __hip_bfloat16* g, __hip_bfloat16* l) {
    __builtin_amdgcn_global_load_lds(
        (const __attribute__((address_space(1))) void*)g,
        (__attribute__((address_space(3))) void*)l,
        16, 0, 0);
}

// -------- prep: dtype detect + offsets cumsum + bias casts (one launch) -----
__global__ void k_prep(const unsigned short* __restrict__ src,
                       const void* __restrict__ b_in, const void* __restrict__ b_out,
                       const int* __restrict__ agents,
                       int* __restrict__ flag, int* __restrict__ offs,
                       float* __restrict__ bfi, float* __restrict__ bfo) {
    __shared__ int sh[256];
    __shared__ int sa[64];
    __shared__ int sflag;
    int tid = threadIdx.x;
    int h = 0;
    for (int i = tid; i < 16384; i += 256) {
        unsigned e = (src[i] >> 7) & 0xFF;
        if (e == 0xFF) h = 1;      // NaN/Inf bit pattern when viewed as bf16 => f32 data
    }
    sh[tid] = h;
    if (tid < 64) sa[tid] = agents[tid];
    __syncthreads();
    if (tid < 64) {
        int v = sh[tid] | sh[tid + 64] | sh[tid + 128] | sh[tid + 192];
        unsigned long long m = __ballot(v != 0);
        if (tid == 0) { flag[0] = (m != 0) ? 1 : 0; sflag = (m != 0) ? 1 : 0; }
        int ex = 0;
        for (int i = 0; i < 64; ++i) { int w = sa[i]; if (i < tid) ex += w; }
        offs[tid] = ex;
        if (tid == 63) offs[64] = ex + sa[63];
    }
    __syncthreads();
    int f = sflag;
    for (int i = tid; i < 1536; i += 256)
        bfi[i] = f ? ((const float*)b_in)[i]
                   : __bfloat162float(((const __hip_bfloat16*)b_in)[i]);
    for (int i = tid; i < 512; i += 256)
        bfo[i] = f ? ((const float*)b_out)[i]
                   : __bfloat162float(((const __hip_bfloat16*)b_out)[i]);
}

// -------- cast A + W_in + W_out to canonical bf16 in one launch -------------
__global__ void k_cast_all(const void* __restrict__ sA, unsigned short* __restrict__ dA, int nA,
                           const void* __restrict__ sWi, unsigned short* __restrict__ dWi, int nWi,
                           const void* __restrict__ sWo, unsigned short* __restrict__ dWo, int nWo,
                           const int* __restrict__ flag) {
    int i = (blockIdx.x * 256 + threadIdx.x) * 4;
    const void* src; unsigned short* dst; int k;
    if (i < nA)            { src = sA;  dst = dA;  k = i; }
    else if (i < nA + nWi) { src = sWi; dst = dWi; k = i - nA; }
    else if (i < nA + nWi + nWo) { src = sWo; dst = dWo; k = i - nA - nWi; }
    else return;
    u16x4 o;
    if (flag[0]) {
        fl4 v = *(const fl4*)((const float*)src + k);
        o[0] = f2b(v[0]); o[1] = f2b(v[1]); o[2] = f2b(v[2]); o[3] = f2b(v[3]);
    } else {
        o = *(const u16x4*)((const unsigned short*)src + k);
    }
    *(u16x4*)(dst + k) = o;
}

// -------- 128x128 GEMM core (k_out), BK=64, 512 thr, counted vmcnt ----------
// Proven round-7 core. LDS chunk L: row = L>>3, seg = (L&7)^(row&7).
// MROWS=false (mfma(wf,af)): m = m0+wm*64+i*16+c ; col = n0+wn*32+j*16+quad*4+r
template<int LDA, bool MROWS>
__device__ __forceinline__ void gemm_core(
    const __hip_bfloat16* __restrict__ A,
    const __hip_bfloat16* __restrict__ W,
    int m0, int n0, int total,
    __hip_bfloat16* As, __hip_bfloat16* Ws,   // each 2*128*64 elements
    f32x4 acc[4][2], int tid)
{
    int lane = tid & 63, quad = lane >> 4, c = lane & 15;
    int wave = tid >> 6;                      // 0..7
    int wm = wave >> 2, wn = wave & 3;

    const __hip_bfloat16* gA[2];
    const __hip_bfloat16* gW[2];
    __hip_bfloat16* lA[2];
    __hip_bfloat16* lW[2];
#pragma unroll
    for (int j = 0; j < 2; ++j) {
        int L = j * 512 + tid;                // 1024 16B-chunks per 128x64 tile
        int row = L >> 3;
        int gseg = (L & 7) ^ (row & 7);
        int ar = m0 + row; if (ar > total - 1) ar = total - 1;
        gA[j] = A + (size_t)ar * LDA + gseg * 8;
        gW[j] = W + (size_t)(n0 + row) * 512 + gseg * 8;
        lA[j] = As + (size_t)(j * 512 + wave * 64) * 8;   // wave-uniform base
        lW[j] = Ws + (size_t)(j * 512 + wave * 64) * 8;
    }

#pragma unroll
    for (int j = 0; j < 2; ++j) gld_lds16(gA[j], lA[j]);
#pragma unroll
    for (int j = 0; j < 2; ++j) gld_lds16(gW[j], lW[j]);

#pragma unroll
    for (int s = 0; s < 8; ++s) {
        const int cur = s & 1;
        const int nxt = cur ^ 1;
        if (s < 7) {
            int k0 = (s + 1) * 64;
#pragma unroll
            for (int j = 0; j < 2; ++j) gld_lds16(gA[j] + k0, lA[j] + nxt * (128 * 64));
#pragma unroll
            for (int j = 0; j < 2; ++j) gld_lds16(gW[j] + k0, lW[j] + nxt * (128 * 64));
            asm volatile("s_waitcnt vmcnt(4)" ::: "memory");
        } else {
            asm volatile("s_waitcnt vmcnt(0)" ::: "memory");
        }
        __builtin_amdgcn_s_barrier();        // B1: buf[cur] staged by all waves
        const __hip_bfloat16* Ab = As + cur * (128 * 64);
        const __hip_bfloat16* Wb = Ws + cur * (128 * 64);
#pragma unroll
        for (int h = 0; h < 2; ++h) {
            bf16x8 af[4], wf[2];
            int ks = quad + 4 * h;
#pragma unroll
            for (int t = 0; t < 4; ++t) {
                int rowa = wm * 64 + t * 16 + c;
                af[t] = *(const bf16x8*)(Ab + (size_t)rowa * 64 + ((ks ^ (rowa & 7)) * 8));
            }
#pragma unroll
            for (int t = 0; t < 2; ++t) {
                int rowb = wn * 32 + t * 16 + c;
                wf[t] = *(const bf16x8*)(Wb + (size_t)rowb * 64 + ((ks ^ (rowb & 7)) * 8));
            }
#pragma unroll
            for (int i = 0; i < 4; ++i)
#pragma unroll
                for (int j = 0; j < 2; ++j)
                    acc[i][j] = MROWS ? mfma16(af[i], wf[j], acc[i][j])
                                      : mfma16(wf[j], af[i], acc[i][j]);
        }
        if (s < 7) __builtin_amdgcn_s_barrier();
    }
}

// -------- 256x256 GEMM core (k_qkv): phase-split counted-vmcnt pipeline -----
// 2 phases per K-tile (16 total). Phase ch computes all 8 row-frags x W-half
// ch (32 MFMA/wave). Stage units: A-tile (4 loads), Wch0 {gW0,gW1}, Wch1
// {gW2,gW3}. Issue: P0(s) -> (s+1).A + (s+1).Wch0 ; P1(s) -> (s+1).Wch1.
// Ledger-derived counted waits (never drain in-loop):
//   P0: vmcnt(2)  [allows this tile's Wch1 in flight]
//   P1: vmcnt(6)  [allows next tile's A+Wch0]        (s==7: vmcnt(0))
// Region safety: a region's last ds_read retires before the issuing phase's
// barrier (reader waves pass it only after their MFMAs consumed the reads).
// MROWS=true  (mfma(af,wf)): m=m0+wm*128+i*16+quad*4+r ; col=n0+ch*128+wn*32+jj*16+c
// MROWS=false (mfma(wf,af)): m=m0+wm*128+i*16+c ; col=n0+ch*128+wn*32+jj*16+quad*4+r
template<bool MROWS>
__device__ __forceinline__ void gemm256_core(
    const __hip_bfloat16* __restrict__ A,
    const __hip_bfloat16* __restrict__ W,
    int m0, int n0, int total,
    __hip_bfloat16* As, __hip_bfloat16* Ws,   // each 2*256*64 elements
    f32x4 acc[8][4], int tid)
{
    int lane = tid & 63, quad = lane >> 4, c = lane & 15;
    int wave = tid >> 6;
    int wm = wave >> 2, wn = wave & 3;

    const __hip_bfloat16* gA[4];
    const __hip_bfloat16* gW[4];
    __hip_bfloat16* lA[4];
    __hip_bfloat16* lW[4];
#pragma unroll
    for (int j = 0; j < 4; ++j) {
        int L = j * 512 + tid;                 // 2048 16B-chunks per 256x64 tile
        int row = L >> 3;
        int gseg = (L & 7) ^ (row & 7);
        int ar = m0 + row; if (ar > total - 1) ar = total - 1;
        gA[j] = A + (size_t)ar * 512 + gseg * 8;
        gW[j] = W + (size_t)(n0 + row) * 512 + gseg * 8;
        lA[j] = As + (size_t)(j * 512 + wave * 64) * 8;   // wave-uniform base
        lW[j] = Ws + (size_t)(j * 512 + wave * 64) * 8;
    }

    // prologue: tile 0 = A(4), Wch0(2), Wch1(2) -- in ledger order
#pragma unroll
    for (int j = 0; j < 4; ++j) gld_lds16(gA[j], lA[j]);
#pragma unroll
    for (int j = 0; j < 4; ++j) gld_lds16(gW[j], lW[j]);

#pragma unroll
    for (int s = 0; s < 8; ++s) {
        const int cur = s & 1;
        const int nxt = cur ^ 1;
        const __hip_bfloat16* Ab = As + cur * (256 * 64);
        const __hip_bfloat16* Wb = Ws + cur * (256 * 64);
#pragma unroll
        for (int ph = 0; ph < 2; ++ph) {
            if (ph == 0)      asm volatile("s_waitcnt vmcnt(2)" ::: "memory");
            else if (s < 7)   asm volatile("s_waitcnt vmcnt(6)" ::: "memory");
            else              asm volatile("s_waitcnt vmcnt(0)" ::: "memory");
            __builtin_amdgcn_s_barrier();     // all waves' needed stages landed;
                                              // all prior-phase ds_reads retired
            if (s < 7) {
                int k0 = (s + 1) * 64;
                if (ph == 0) {
#pragma unroll
                    for (int j = 0; j < 4; ++j) gld_lds16(gA[j] + k0, lA[j] + nxt * (256 * 64));
#pragma unroll
                    for (int j = 0; j < 2; ++j) gld_lds16(gW[j] + k0, lW[j] + nxt * (256 * 64));
                } else {
#pragma unroll
                    for (int j = 2; j < 4; ++j) gld_lds16(gW[j] + k0, lW[j] + nxt * (256 * 64));
                }
            }
#pragma unroll
            for (int h = 0; h < 2; ++h) {
                int ks = quad + 4 * h;
                bf16x8 af[8], wf[2];
#pragma unroll
                for (int t = 0; t < 8; ++t) {
                    int rowa = wm * 128 + t * 16 + c;
                    af[t] = *(const bf16x8*)(Ab + (size_t)rowa * 64 + ((ks ^ (rowa & 7)) * 8));
                }
#pragma unroll
                for (int t = 0; t < 2; ++t) {
                    int rowb = ph * 128 + wn * 32 + t * 16 + c;
                    wf[t] = *(const bf16x8*)(Wb + (size_t)rowb * 64 + ((ks ^ (rowb & 7)) * 8));
                }
                __builtin_amdgcn_s_setprio(1);
#pragma unroll
                for (int i = 0; i < 8; ++i)
#pragma unroll
                    for (int j = 0; j < 2; ++j) {
                        int jj = ph * 2 + j;
                        acc[i][jj] = MROWS ? mfma16(af[i], wf[j], acc[i][jj])
                                           : mfma16(wf[j], af[i], acc[i][jj]);
                    }
                __builtin_amdgcn_s_setprio(0);
            }
        }
    }
}

// -------- QKV projection (256^2 tiles, 16-phase pipeline) -------------------
// qP[bh][256][64], kP[bh][256][64], vT[bh][64][256]  (bh = sample*8 + head)
// Bijective XCD-chunked swizzle (m204): consecutive wg share the A row-tile
// within one XCD -> A fetched ~once; all 6 W-panels (1.5MB) L2-resident.
__global__ __launch_bounds__(512, 2) void k_qkv(
    const __hip_bfloat16* __restrict__ A,    // [total][512]
    const __hip_bfloat16* __restrict__ W,    // [1536][512]
    const float* __restrict__ bias,          // [1536]
    const int* __restrict__ offs,            // [65]
    __hip_bfloat16* __restrict__ qP,         // [512][256][64]
    __hip_bfloat16* __restrict__ kP,         // [512][256][64]
    __hip_bfloat16* __restrict__ vT,         // [512][64][256]
    int total)
{
    __shared__ __hip_bfloat16 As[2 * 256 * 64];
    __shared__ __hip_bfloat16 Ws[2 * 256 * 64];
    __shared__ int s_off[65];
    int nwg = gridDim.x;
    int bid = blockIdx.x;
    int xcd = bid & 7, idx = bid >> 3;
    int q = nwg >> 3, r = nwg & 7;
    int wg = (xcd < r ? xcd * (q + 1) : r * (q + 1) + (xcd - r) * q) + idx;
    int rb = wg / 6;
    int cb = wg - rb * 6;
    int n0 = cb * 256;
    int m0 = rb * 256;
    int tid = threadIdx.x;
    if (tid < 65) s_off[tid] = offs[tid];
    int lane = tid & 63, quad = lane >> 4, c = lane & 15;
    int wave = tid >> 6, wm = wave >> 2, wn = wave & 3;
    f32x4 z = {0.f, 0.f, 0.f, 0.f};
    f32x4 acc[8][4] = {{z,z,z,z},{z,z,z,z},{z,z,z,z},{z,z,z,z},
                       {z,z,z,z},{z,z,z,z},{z,z,z,z},{z,z,z,z}};

    if (n0 < 1024) {
        // ---- Q/K region: transposed fragments -> packed per-(b,h) slices ----
        gemm256_core<false>(A, W, m0, n0, total, As, Ws, acc, tid);
        __hip_bfloat16* dst = (n0 < 512) ? qP : kP;
        int nb = n0 & 511;                        // 0 or 256
        fl4 bv4[4];
#pragma unroll
        for (int jj = 0; jj < 4; ++jj)
            bv4[jj] = *(const fl4*)&bias[n0 + (jj >> 1) * 128 + wn * 32 + (jj & 1) * 16 + quad * 4];
#pragma unroll
        for (int i = 0; i < 8; ++i) {
            int m = m0 + wm * 128 + i * 16 + c;
            if (m >= total) continue;
            int lo = bsearch_off(s_off, m);
            int vs = m - s_off[lo];
#pragma unroll
            for (int jj = 0; jj < 4; ++jj) {
                int ch = jj >> 1, j2 = jj & 1;
                int head = (nb >> 6) + ch * 2 + (wn >> 1);   // wave-uniform
                int dcol = (wn & 1) * 32 + j2 * 16 + quad * 4;
                size_t rowp = ((size_t)(lo * 8 + head) * 256 + vs) * 64;
                u16x4 o;
#pragma unroll
                for (int r2 = 0; r2 < 4; ++r2) o[r2] = f2b(acc[i][jj][r2] + bv4[jj][r2]);
                *(u16x4*)&dst[rowp + dcol] = o;
            }
        }
    } else {
        // ---- V region: row-major fragments (4 consecutive m per lane) ----
        gemm256_core<true>(A, W, m0, n0, total, As, Ws, acc, tid);
        float bv[4];
#pragma unroll
        for (int jj = 0; jj < 4; ++jj)
            bv[jj] = bias[n0 + (jj >> 1) * 128 + wn * 32 + (jj & 1) * 16 + c];
#pragma unroll
        for (int i = 0; i < 8; ++i) {
            int m_base = m0 + wm * 128 + i * 16 + quad * 4;
            if (m_base >= total) continue;
            int lo = bsearch_off(s_off, m_base);
            bool vec = (m_base + 3 < total) && (s_off[lo + 1] > m_base + 3);
            if (vec) {
                int vs = m_base - s_off[lo];
#pragma unroll
                for (int jj = 0; jj < 4; ++jj) {
                    int vc = n0 - 1024 + (jj >> 1) * 128 + wn * 32 + (jj & 1) * 16 + c;
                    size_t idxv = ((size_t)(lo * 8 + (vc >> 6)) * 64 + (vc & 63)) * 256 + vs;
                    u16x4 o;
#pragma unroll
                    for (int r2 = 0; r2 < 4; ++r2) o[r2] = f2b(acc[i][jj][r2] + bv[jj]);
                    ((u16x4u*)&vT[idxv])->v = o;
                }
            } else {
#pragma unroll
                for (int r2 = 0; r2 < 4; ++r2) {
                    int m = m_base + r2;
                    if (m >= total) continue;
                    int lo2 = bsearch_off(s_off, m);
                    int vs2 = m - s_off[lo2];
#pragma unroll
                    for (int jj = 0; jj < 4; ++jj) {
                        int vc = n0 - 1024 + (jj >> 1) * 128 + wn * 32 + (jj & 1) * 16 + c;
                        vT[((size_t)(lo2 * 8 + (vc >> 6)) * 64 + (vc & 63)) * 256 + vs2] =
                            __float2bfloat16(acc[i][jj][r2] + bv[jj]);
                    }
                }
            }
        }
    }
}

// -------- attention: block=(b,h), 4 waves, 4 q-tiles/wave, packed streams ---
// K/V register prefetch DEPTH 2: three static buffers (A,B,C), unroll-3
// rotation, all indices compile-time (rule #20).
__global__ __launch_bounds__(256, 2) void k_attn(
    const __hip_bfloat16* __restrict__ qP,   // [512][256][64]
    const __hip_bfloat16* __restrict__ kP,   // [512][256][64]
    const __hip_bfloat16* __restrict__ vT,   // [512][64][256]
    __hip_bfloat16* __restrict__ ctx,        // [total][512]
    const int* __restrict__ agents,
    const int* __restrict__ offs)
{
    __shared__ __attribute__((aligned(16))) char Pl[4][16 * 80];  // [wave][q:16][key:32 @stride 80B]
    int bh = blockIdx.x;
    int b = bh >> 3, h = bh & 7;
    int n = agents[b];
    int off = offs[b];
    int qtiles = (n + 15) >> 4;              // 8..16
    int stmax = (qtiles + 1) >> 1;           // 32-key steps: 4..8
    int tid = threadIdx.x;
    int wave = tid >> 6, lane = tid & 63, quad = lane >> 4, c = lane & 15;
    const __hip_bfloat16* qbase = qP + (size_t)bh * 256 * 64;
    const __hip_bfloat16* kbase = kP + (size_t)bh * 256 * 64 + quad * 8;
    const __hip_bfloat16* vbase = vT + (size_t)bh * 64 * 256;
    char* Plw = &Pl[wave][0];

    bf16x8 qB[4][2];
    int nt = 0;
#pragma unroll
    for (int t = 0; t < 4; ++t) {
        int qt = wave + 4 * t;
        if (qt < qtiles) {
            nt = t + 1;
            int qr = qt * 16 + c; if (qr > n - 1) qr = n - 1;
            const __hip_bfloat16* qp = qbase + (size_t)qr * 64 + quad * 8;
            qB[t][0] = *(const bf16x8*)qp;
            qB[t][1] = *(const bf16x8*)(qp + 32);
        }
    }

    f32x4 z = {0.f, 0.f, 0.f, 0.f};
    f32x4 O[4][4] = {{z,z,z,z},{z,z,z,z},{z,z,z,z},{z,z,z,z}};  // [q-tile][d-tile], O^T layout
    float sm[4] = {0.f, 0.f, 0.f, 0.f};

    auto LK = [&](int st, bf16x8 kA[2][2], bf16x8 vA[4]) {
        int k0 = st * 32;
#pragma unroll
        for (int ti = 0; ti < 2; ++ti) {
            int kr = k0 + ti * 16 + c; if (kr > n - 1) kr = n - 1;
            const __hip_bfloat16* kp = kbase + (size_t)kr * 64;
            kA[ti][0] = *(const bf16x8*)kp;
            kA[ti][1] = *(const bf16x8*)(kp + 32);
        }
#pragma unroll
        for (int dt = 0; dt < 4; ++dt)
            vA[dt] = *(const bf16x8*)(vbase + (size_t)(dt * 16 + c) * 256 + k0 + quad * 8);
    };

    auto CMP = [&](int st, bf16x8 kA[2][2], bf16x8 vA[4]) {
        int k0 = st * 32;
#pragma unroll
        for (int t = 0; t < 4; ++t) {
            if (t < nt) {
#pragma unroll
                for (int ti = 0; ti < 2; ++ti) {
                    f32x4 s = mfma16(kA[ti][0], qB[t][0], z);
                    s = mfma16(kA[ti][1], qB[t][1], s);
                    int kbase_i = k0 + ti * 16 + quad * 4;   // this lane's 4 keys
                    float p0 = (kbase_i + 0 < n) ? __expf(s[0] * 0.125f) : 0.f;
                    float p1 = (kbase_i + 1 < n) ? __expf(s[1] * 0.125f) : 0.f;
                    float p2 = (kbase_i + 2 < n) ? __expf(s[2] * 0.125f) : 0.f;
                    float p3 = (kbase_i + 3 < n) ? __expf(s[3] * 0.125f) : 0.f;
                    sm[t] += (p0 + p1) + (p2 + p3);
                    ui2 dw;
                    dw[0] = (unsigned)f2b(p0) | ((unsigned)f2b(p1) << 16);
                    dw[1] = (unsigned)f2b(p2) | ((unsigned)f2b(p3) << 16);
                    *(ui2*)(Plw + c * 80 + ti * 32 + quad * 8) = dw;
                }
                bf16x8 pB = *(const bf16x8*)(Plw + c * 80 + quad * 16);
#pragma unroll
                for (int dt = 0; dt < 4; ++dt)
                    O[t][dt] = mfma16(vA[dt], pB, O[t][dt]);
            }
        }
    };

    bf16x8 kA[2][2], vA[4], kB[2][2], vB[4], kC[2][2], vC[4];
    LK(0, kA, vA);
    if (1 < stmax) LK(1, kB, vB);
    for (int st = 0; st < stmax; st += 3) {
        if (st + 2 < stmax) LK(st + 2, kC, vC);
        CMP(st, kA, vA);
        if (st + 3 < stmax) LK(st + 3, kA, vA);
        if (st + 1 < stmax) CMP(st + 1, kB, vB);
        if (st + 4 < stmax) LK(st + 4, kB, vB);
        if (st + 2 < stmax) CMP(st + 2, kC, vC);
    }

#pragma unroll
    for (int t = 0; t < 4; ++t) {
        if (t < nt) {
            float v = sm[t];
            v += __shfl_xor(v, 16);
            v += __shfl_xor(v, 32);
            float iv = 1.0f / v;
            int q = (wave + 4 * t) * 16 + c;
            if (q < n) {
                size_t row = (size_t)(off + q) * 512 + h * 64;
#pragma unroll
                for (int dt = 0; dt < 4; ++dt) {
                    u16x4 o;
#pragma unroll
                    for (int r = 0; r < 4; ++r) o[r] = f2b(O[t][dt][r] * iv);
                    *(u16x4*)&ctx[row + dt * 16 + quad * 4] = o;
                }
            }
        }
    }
}

// -------- output projection + pad-row zeroing (merged, one launch) ----------
__global__ __launch_bounds__(512, 4) void k_out(
    const __hip_bfloat16* __restrict__ A,    // ctx [total][512]
    const __hip_bfloat16* __restrict__ W,    // [512][512]
    const float* __restrict__ bias,          // [512]
    const int* __restrict__ offs,            // [65]
    const int* __restrict__ agents,
    void* __restrict__ out,                  // [64][254][512] f32 or bf16
    const int* __restrict__ flag,
    int total, int MT)
{
    __shared__ __hip_bfloat16 As[2 * 128 * 64];
    __shared__ __hip_bfloat16 Ws[2 * 128 * 64];
    __shared__ int s_off[65];
    int l = blockIdx.x;
    int MTpad = ((MT + 7) >> 3) << 3;
    int tid = threadIdx.x;
    if (l >= 4 * MTpad) {
        // ---- zero-pad block for sample b ----
        int b = l - 4 * MTpad;
        int n = agents[b];
        int esz = flag[0] ? 4 : 2;
        long long base = ((long long)b * 254 + n) * 512 * esz;
        long long bytes = (long long)(254 - n) * 512 * esz;
        for (long long i = (long long)tid * 16; i < bytes; i += (long long)512 * 16)
            *(i32x4*)((char*)out + base + i) = (i32x4){0, 0, 0, 0};
        return;
    }
    int inner = l >> 3;
    int cb = inner & 3;
    int rb = (l & 7) + 8 * (inner >> 2);
    if (rb >= MT) return;
    int n0 = cb * 128;
    int m0 = rb * 128;
    if (tid < 65) s_off[tid] = offs[tid];
    f32x4 z = {0.f, 0.f, 0.f, 0.f};
    f32x4 acc[4][2] = {{z,z},{z,z},{z,z},{z,z}};
    gemm_core<512, false>(A, W, m0, n0, total, As, Ws, acc, tid);

    int f32m = flag[0];
    int lane = tid & 63, quad = lane >> 4, c = lane & 15;
    int wave = tid >> 6, wm = wave >> 2, wn = wave & 3;
    fl4 bv4[2];
#pragma unroll
    for (int j = 0; j < 2; ++j)
        bv4[j] = *(const fl4*)&bias[n0 + wn * 32 + j * 16 + quad * 4];
#pragma unroll
    for (int i = 0; i < 4; ++i) {
        int m = m0 + wm * 64 + i * 16 + c;
        if (m >= total) continue;
        int lo = bsearch_off(s_off, m);
        int os_ = m - s_off[lo];
        size_t rowb = ((size_t)(lo * 254 + os_)) * 512;
#pragma unroll
        for (int j = 0; j < 2; ++j) {
            int col0 = n0 + wn * 32 + j * 16 + quad * 4;
            if (f32m) {
                fl4 o;
#pragma unroll
                for (int r = 0; r < 4; ++r) o[r] = acc[i][j][r] + bv4[j][r];
                *(fl4*)&((float*)out)[rowb + col0] = o;
            } else {
                u16x4 o;
#pragma unroll
                for (int r = 0; r < 4; ++r) o[r] = f2b(acc[i][j][r] + bv4[j][r]);
                *(u16x4*)&((__hip_bfloat16*)out)[rowb + col0] = o;
            }
        }
    }
}

extern "C" void kernel_launch(void* const* d_in, const int* in_sizes, int n_in,
                              void* d_out, int out_size, void* d_ws, size_t ws_size,
                              hipStream_t stream) {
    const void* att_in = d_in[0];
    const void* w_in   = d_in[1];
    const void* b_in   = d_in[2];
    const void* w_out  = d_in[3];
    const void* b_out  = d_in[4];
    const int* agents  = (const int*)d_in[5];
    int total = in_sizes[0] / 512;

    char* p = (char*)d_ws;
    int* flag  = (int*)p;                 p += 256;
    int* offs  = (int*)p;                 p += 512;
    float* bfi = (float*)p;               p += 1536 * 4;
    float* bfo = (float*)p;               p += 512 * 4;
    __hip_bfloat16* WinBf  = (__hip_bfloat16*)p;  p += (size_t)1536 * 512 * 2;
    __hip_bfloat16* WoutBf = (__hip_bfloat16*)p;  p += (size_t)512 * 512 * 2;
    __hip_bfloat16* Abf    = (__hip_bfloat16*)p;  p += (size_t)total * 512 * 2;
    __hip_bfloat16* qP     = (__hip_bfloat16*)p;  p += (size_t)512 * 256 * 64 * 2;
    __hip_bfloat16* kP     = (__hip_bfloat16*)p;  p += (size_t)512 * 256 * 64 * 2;
    __hip_bfloat16* vT     = (__hip_bfloat16*)p;  p += (size_t)512 * 64 * 256 * 2;
    __hip_bfloat16* ctx    = (__hip_bfloat16*)p;  p += (size_t)total * 512 * 2;

    int nA = total * 512, nWi = 1536 * 512, nWo = 512 * 512;
    int ntot = nA + nWi + nWo;

    k_prep<<<1, 256, 0, stream>>>((const unsigned short*)att_in, b_in, b_out,
                                  agents, flag, offs, bfi, bfo);
    k_cast_all<<<(ntot / 4 + 255) / 256, 256, 0, stream>>>(
        att_in, (unsigned short*)Abf, nA,
        w_in,   (unsigned short*)WinBf, nWi,
        w_out,  (unsigned short*)WoutBf, nWo, flag);

    int MT = (total + 127) / 128;
    int MTpad = ((MT + 7) / 8) * 8;
    int MT256 = (total + 255) / 256;
    k_qkv<<<6 * MT256, 512, 0, stream>>>(Abf, WinBf, bfi, offs, qP, kP, vT, total);
    k_attn<<<512, 256, 0, stream>>>(qP, kP, vT, ctx, agents, offs);
    k_out<<<4 * MTpad + 64, 512, 0, stream>>>(ctx, WoutBf, bfo, offs, agents,
                                              d_out, flag, total, MT);
}

// Round 10
// 171.226 us; speedup vs baseline: 1.1143x; 1.1143x over previous
//
#include <hip/hip_runtime.h>
#include <hip/hip_bf16.h>

typedef __attribute__((ext_vector_type(8))) short bf16x8;
typedef __attribute__((ext_vector_type(4))) float f32x4;
typedef __attribute__((ext_vector_type(4))) int i32x4;
typedef __attribute__((ext_vector_type(4))) unsigned short u16x4;
typedef __attribute__((ext_vector_type(2))) unsigned ui2;
typedef __attribute__((ext_vector_type(4))) float fl4;

struct __attribute__((packed)) u16x4u { u16x4 v; };   // unaligned vector store

__device__ __forceinline__ f32x4 mfma16(bf16x8 a, bf16x8 b, f32x4 c) {
    return __builtin_amdgcn_mfma_f32_16x16x32_bf16(a, b, c, 0, 0, 0);
}

__device__ __forceinline__ unsigned short f2b(float f) {
    unsigned u = __float_as_uint(f);
    unsigned r = (u + 0x7FFF + ((u >> 16) & 1)) >> 16;
    return (unsigned short)r;
}

__device__ __forceinline__ int bsearch_off(const int* s_off, int m) {
    int lo = 0, hi = 63;
    while (lo < hi) {
        int mid = (lo + hi + 1) >> 1;
        if (s_off[mid] <= m) lo = mid; else hi = mid - 1;
    }
    return lo;
}

// async global->LDS, 16B per lane; lds base must be wave-uniform (HW adds lane*16)
__device__ __forceinline__ void gld_lds16(const __hip_bfloat16* g, __hip_bfloat16* l) {
    __builtin_amdgcn_global_load_lds(
        (const __attribute__((address_space(1))) void*)g,
        (__attribute__((address_space(3))) void*)l,
        16, 0, 0);
}

// -------- prep: dtype detect + offsets cumsum + bias casts (one launch) -----
__global__ void k_prep(const unsigned short* __restrict__ src,
                       const void* __restrict__ b_in, const void* __restrict__ b_out,
                       const int* __restrict__ agents,
                       int* __restrict__ flag, int* __restrict__ offs,
                       float* __restrict__ bfi, float* __restrict__ bfo) {
    __shared__ int sh[256];
    __shared__ int sa[64];
    __shared__ int sflag;
    int tid = threadIdx.x;
    int h = 0;
    for (int i = tid; i < 16384; i += 256) {
        unsigned e = (src[i] >> 7) & 0xFF;
        if (e == 0xFF) h = 1;      // NaN/Inf bit pattern when viewed as bf16 => f32 data
    }
    sh[tid] = h;
    if (tid < 64) sa[tid] = agents[tid];
    __syncthreads();
    if (tid < 64) {
        int v = sh[tid] | sh[tid + 64] | sh[tid + 128] | sh[tid + 192];
        unsigned long long m = __ballot(v != 0);
        if (tid == 0) { flag[0] = (m != 0) ? 1 : 0; sflag = (m != 0) ? 1 : 0; }
        int ex = 0;
        for (int i = 0; i < 64; ++i) { int w = sa[i]; if (i < tid) ex += w; }
        offs[tid] = ex;
        if (tid == 63) offs[64] = ex + sa[63];
    }
    __syncthreads();
    int f = sflag;
    for (int i = tid; i < 1536; i += 256)
        bfi[i] = f ? ((const float*)b_in)[i]
                   : __bfloat162float(((const __hip_bfloat16*)b_in)[i]);
    for (int i = tid; i < 512; i += 256)
        bfo[i] = f ? ((const float*)b_out)[i]
                   : __bfloat162float(((const __hip_bfloat16*)b_out)[i]);
}

// -------- cast A + W_in + W_out to canonical bf16 in one launch -------------
__global__ void k_cast_all(const void* __restrict__ sA, unsigned short* __restrict__ dA, int nA,
                           const void* __restrict__ sWi, unsigned short* __restrict__ dWi, int nWi,
                           const void* __restrict__ sWo, unsigned short* __restrict__ dWo, int nWo,
                           const int* __restrict__ flag) {
    int i = (blockIdx.x * 256 + threadIdx.x) * 4;
    const void* src; unsigned short* dst; int k;
    if (i < nA)            { src = sA;  dst = dA;  k = i; }
    else if (i < nA + nWi) { src = sWi; dst = dWi; k = i - nA; }
    else if (i < nA + nWi + nWo) { src = sWo; dst = dWo; k = i - nA - nWi; }
    else return;
    u16x4 o;
    if (flag[0]) {
        fl4 v = *(const fl4*)((const float*)src + k);
        o[0] = f2b(v[0]); o[1] = f2b(v[1]); o[2] = f2b(v[2]); o[3] = f2b(v[3]);
    } else {
        o = *(const u16x4*)((const unsigned short*)src + k);
    }
    *(u16x4*)(dst + k) = o;
}

// -------- 128x128 GEMM core, BK=64, 512 threads (8 waves, 2x4) --------------
// BEST MEASURED (round 7). Counted-vmcnt 2-phase double buffer, 8 waves/block:
// per-wave output 64x32 (acc[4][2]), 4 staging loads/thread, vmcnt(4) counted.
// LDS 64KB -> 2 blocks/CU -> 16 waves/CU (4/SIMD): co-resident blocks cover
// the per-step load walls (proven: 1-block/CU 256^2 variants lose 1.5x even
// with perfect L2 mapping + phase-split + setprio -- R6/R8).
//   B1: vmcnt(4) + s_barrier  => buf[cur] fully staged
//   B2: s_barrier after MFMA  => safe to overwrite buf[cur] next iter
// LDS chunk L (16B) holds global (row = L>>3, seg = (L&7) ^ (row&7)).
// MROWS=true  (mfma(af,wf)): m = m0+wm*64+i*16+quad*4+r ; col = n0+wn*32+j*16+c
// MROWS=false (mfma(wf,af)): m = m0+wm*64+i*16+c ; col = n0+wn*32+j*16+quad*4+r
template<int LDA, bool MROWS>
__device__ __forceinline__ void gemm_core(
    const __hip_bfloat16* __restrict__ A,
    const __hip_bfloat16* __restrict__ W,
    int m0, int n0, int total,
    __hip_bfloat16* As, __hip_bfloat16* Ws,   // each 2*128*64 elements
    f32x4 acc[4][2], int tid)
{
    int lane = tid & 63, quad = lane >> 4, c = lane & 15;
    int wave = tid >> 6;                      // 0..7
    int wm = wave >> 2, wn = wave & 3;

    const __hip_bfloat16* gA[2];
    const __hip_bfloat16* gW[2];
    __hip_bfloat16* lA[2];
    __hip_bfloat16* lW[2];
#pragma unroll
    for (int j = 0; j < 2; ++j) {
        int L = j * 512 + tid;                // 1024 16B-chunks per 128x64 tile
        int row = L >> 3;
        int gseg = (L & 7) ^ (row & 7);
        int ar = m0 + row; if (ar > total - 1) ar = total - 1;
        gA[j] = A + (size_t)ar * LDA + gseg * 8;
        gW[j] = W + (size_t)(n0 + row) * 512 + gseg * 8;
        lA[j] = As + (size_t)(j * 512 + wave * 64) * 8;   // wave-uniform base
        lW[j] = Ws + (size_t)(j * 512 + wave * 64) * 8;
    }

    // prologue: issue K-tile 0 into buffer 0 (4 loads/thread outstanding)
#pragma unroll
    for (int j = 0; j < 2; ++j) gld_lds16(gA[j], lA[j]);
#pragma unroll
    for (int j = 0; j < 2; ++j) gld_lds16(gW[j], lW[j]);

#pragma unroll
    for (int s = 0; s < 8; ++s) {
        const int cur = s & 1;
        const int nxt = cur ^ 1;
        if (s < 7) {
            int k0 = (s + 1) * 64;
#pragma unroll
            for (int j = 0; j < 2; ++j) gld_lds16(gA[j] + k0, lA[j] + nxt * (128 * 64));
#pragma unroll
            for (int j = 0; j < 2; ++j) gld_lds16(gW[j] + k0, lW[j] + nxt * (128 * 64));
            // wait only tile s's 4 loads; tile s+1's 4 stay in flight
            asm volatile("s_waitcnt vmcnt(4)" ::: "memory");
        } else {
            asm volatile("s_waitcnt vmcnt(0)" ::: "memory");
        }
        __builtin_amdgcn_s_barrier();        // B1: buf[cur] staged by all waves
        const __hip_bfloat16* Ab = As + cur * (128 * 64);
        const __hip_bfloat16* Wb = Ws + cur * (128 * 64);
#pragma unroll
        for (int h = 0; h < 2; ++h) {
            bf16x8 af[4], wf[2];
            int ks = quad + 4 * h;
#pragma unroll
            for (int t = 0; t < 4; ++t) {
                int rowa = wm * 64 + t * 16 + c;
                af[t] = *(const bf16x8*)(Ab + (size_t)rowa * 64 + ((ks ^ (rowa & 7)) * 8));
            }
#pragma unroll
            for (int t = 0; t < 2; ++t) {
                int rowb = wn * 32 + t * 16 + c;
                wf[t] = *(const bf16x8*)(Wb + (size_t)rowb * 64 + ((ks ^ (rowb & 7)) * 8));
            }
#pragma unroll
            for (int i = 0; i < 4; ++i)
#pragma unroll
                for (int j = 0; j < 2; ++j)
                    acc[i][j] = MROWS ? mfma16(af[i], wf[j], acc[i][j])
                                      : mfma16(wf[j], af[i], acc[i][j]);
        }
        // B2: all waves done reading buf[cur]; next iter may overwrite it.
        if (s < 7) __builtin_amdgcn_s_barrier();
    }
}

// -------- QKV projection into PACKED per-(b,h) layouts ----------------------
// qP[bh][256][64], kP[bh][256][64], vT[bh][64][256]  (bh = sample*8 + head)
// Grid: 12*MTpad blocks (XCD swizzle via l&7), 512 threads.
__global__ __launch_bounds__(512, 4) void k_qkv(
    const __hip_bfloat16* __restrict__ A,    // [total][512]
    const __hip_bfloat16* __restrict__ W,    // [1536][512]
    const float* __restrict__ bias,          // [1536]
    const int* __restrict__ offs,            // [65]
    __hip_bfloat16* __restrict__ qP,         // [512][256][64]
    __hip_bfloat16* __restrict__ kP,         // [512][256][64]
    __hip_bfloat16* __restrict__ vT,         // [512][64][256]
    int total, int MT)
{
    __shared__ __hip_bfloat16 As[2 * 128 * 64];
    __shared__ __hip_bfloat16 Ws[2 * 128 * 64];
    __shared__ int s_off[65];
    int l = blockIdx.x;
    int inner = l >> 3;
    int cb = inner % 12;
    int rb = (l & 7) + 8 * (inner / 12);
    if (rb >= MT) return;
    int n0 = cb * 128;
    int m0 = rb * 128;
    int tid = threadIdx.x;
    if (tid < 65) s_off[tid] = offs[tid];
    int lane = tid & 63, quad = lane >> 4, c = lane & 15;
    int wave = tid >> 6, wm = wave >> 2, wn = wave & 3;
    f32x4 z = {0.f, 0.f, 0.f, 0.f};
    f32x4 acc[4][2] = {{z,z},{z,z},{z,z},{z,z}};

    if (n0 < 1024) {
        // ---- Q/K region: transposed fragments -> packed per-(b,h) slices ----
        gemm_core<512, false>(A, W, m0, n0, total, As, Ws, acc, tid);
        __hip_bfloat16* dst = (n0 < 512) ? qP : kP;
        int nb = n0 & 511;
        int head = (nb + wn * 32) >> 6;          // constant per wave (j*16+quad*4 < 32)
        int cb32 = (wn & 1) * 32;                // col offset within head
        fl4 bv4[2];
#pragma unroll
        for (int j = 0; j < 2; ++j)
            bv4[j] = *(const fl4*)&bias[n0 + wn * 32 + j * 16 + quad * 4];
#pragma unroll
        for (int i = 0; i < 4; ++i) {
            int m = m0 + wm * 64 + i * 16 + c;
            if (m >= total) continue;
            int lo = bsearch_off(s_off, m);
            int vs = m - s_off[lo];
            size_t rowp = ((size_t)(lo * 8 + head) * 256 + vs) * 64;
#pragma unroll
            for (int j = 0; j < 2; ++j) {
                int dcol = cb32 + j * 16 + quad * 4;
                u16x4 o;
#pragma unroll
                for (int r = 0; r < 4; ++r) o[r] = f2b(acc[i][j][r] + bv4[j][r]);
                *(u16x4*)&dst[rowp + dcol] = o;
            }
        }
    } else {
        // ---- V region: row-major fragments (4 consecutive m per lane) ----
        gemm_core<512, true>(A, W, m0, n0, total, As, Ws, acc, tid);
        float bv[2];
#pragma unroll
        for (int j = 0; j < 2; ++j) bv[j] = bias[n0 + wn * 32 + j * 16 + c];
#pragma unroll
        for (int i = 0; i < 4; ++i) {
            int m_base = m0 + wm * 64 + i * 16 + quad * 4;
            if (m_base >= total) continue;
            int lo = bsearch_off(s_off, m_base);
            bool vec = (m_base + 3 < total) && (s_off[lo + 1] > m_base + 3);
            if (vec) {
                int vs = m_base - s_off[lo];
#pragma unroll
                for (int j = 0; j < 2; ++j) {
                    int vc = n0 - 1024 + wn * 32 + j * 16 + c;
                    size_t idx = ((size_t)(lo * 8 + (vc >> 6)) * 64 + (vc & 63)) * 256 + vs;
                    u16x4 o;
#pragma unroll
                    for (int r = 0; r < 4; ++r) o[r] = f2b(acc[i][j][r] + bv[j]);
                    ((u16x4u*)&vT[idx])->v = o;
                }
            } else {
#pragma unroll
                for (int r = 0; r < 4; ++r) {
                    int m = m_base + r;
                    if (m >= total) continue;
                    int lo2 = bsearch_off(s_off, m);
                    int vs2 = m - s_off[lo2];
#pragma unroll
                    for (int j = 0; j < 2; ++j) {
                        int vc = n0 - 1024 + wn * 32 + j * 16 + c;
                        vT[((size_t)(lo2 * 8 + (vc >> 6)) * 64 + (vc & 63)) * 256 + vs2] =
                            __float2bfloat16(acc[i][j][r] + bv[j]);
                    }
                }
            }
        }
    }
}

// -------- attention: block=(b,h), 4 waves, 4 q-tiles/wave, packed streams ---
// K/V register prefetch DEPTH 2: three static buffers (A,B,C), unroll-3
// rotation, all indices compile-time (rule #20).
__global__ __launch_bounds__(256, 2) void k_attn(
    const __hip_bfloat16* __restrict__ qP,   // [512][256][64]
    const __hip_bfloat16* __restrict__ kP,   // [512][256][64]
    const __hip_bfloat16* __restrict__ vT,   // [512][64][256]
    __hip_bfloat16* __restrict__ ctx,        // [total][512]
    const int* __restrict__ agents,
    const int* __restrict__ offs)
{
    __shared__ __attribute__((aligned(16))) char Pl[4][16 * 80];  // [wave][q:16][key:32 @stride 80B]
    int bh = blockIdx.x;
    int b = bh >> 3, h = bh & 7;
    int n = agents[b];
    int off = offs[b];
    int qtiles = (n + 15) >> 4;              // 8..16
    int stmax = (qtiles + 1) >> 1;           // 32-key steps: 4..8
    int tid = threadIdx.x;
    int wave = tid >> 6, lane = tid & 63, quad = lane >> 4, c = lane & 15;
    const __hip_bfloat16* qbase = qP + (size_t)bh * 256 * 64;
    const __hip_bfloat16* kbase = kP + (size_t)bh * 256 * 64 + quad * 8;
    const __hip_bfloat16* vbase = vT + (size_t)bh * 64 * 256;
    char* Plw = &Pl[wave][0];

    bf16x8 qB[4][2];
    int nt = 0;
#pragma unroll
    for (int t = 0; t < 4; ++t) {
        int qt = wave + 4 * t;
        if (qt < qtiles) {
            nt = t + 1;
            int qr = qt * 16 + c; if (qr > n - 1) qr = n - 1;
            const __hip_bfloat16* qp = qbase + (size_t)qr * 64 + quad * 8;
            qB[t][0] = *(const bf16x8*)qp;
            qB[t][1] = *(const bf16x8*)(qp + 32);
        }
    }

    f32x4 z = {0.f, 0.f, 0.f, 0.f};
    f32x4 O[4][4] = {{z,z,z,z},{z,z,z,z},{z,z,z,z},{z,z,z,z}};  // [q-tile][d-tile], O^T layout
    float sm[4] = {0.f, 0.f, 0.f, 0.f};

    auto LK = [&](int st, bf16x8 kA[2][2], bf16x8 vA[4]) {
        int k0 = st * 32;
#pragma unroll
        for (int ti = 0; ti < 2; ++ti) {
            int kr = k0 + ti * 16 + c; if (kr > n - 1) kr = n - 1;
            const __hip_bfloat16* kp = kbase + (size_t)kr * 64;
            kA[ti][0] = *(const bf16x8*)kp;
            kA[ti][1] = *(const bf16x8*)(kp + 32);
        }
#pragma unroll
        for (int dt = 0; dt < 4; ++dt)
            vA[dt] = *(const bf16x8*)(vbase + (size_t)(dt * 16 + c) * 256 + k0 + quad * 8);
    };

    auto CMP = [&](int st, bf16x8 kA[2][2], bf16x8 vA[4]) {
        int k0 = st * 32;
#pragma unroll
        for (int t = 0; t < 4; ++t) {
            if (t < nt) {
#pragma unroll
                for (int ti = 0; ti < 2; ++ti) {
                    f32x4 s = mfma16(kA[ti][0], qB[t][0], z);
                    s = mfma16(kA[ti][1], qB[t][1], s);
                    int kbase_i = k0 + ti * 16 + quad * 4;   // this lane's 4 keys
                    float p0 = (kbase_i + 0 < n) ? __expf(s[0] * 0.125f) : 0.f;
                    float p1 = (kbase_i + 1 < n) ? __expf(s[1] * 0.125f) : 0.f;
                    float p2 = (kbase_i + 2 < n) ? __expf(s[2] * 0.125f) : 0.f;
                    float p3 = (kbase_i + 3 < n) ? __expf(s[3] * 0.125f) : 0.f;
                    sm[t] += (p0 + p1) + (p2 + p3);
                    ui2 dw;
                    dw[0] = (unsigned)f2b(p0) | ((unsigned)f2b(p1) << 16);
                    dw[1] = (unsigned)f2b(p2) | ((unsigned)f2b(p3) << 16);
                    *(ui2*)(Plw + c * 80 + ti * 32 + quad * 8) = dw;
                }
                bf16x8 pB = *(const bf16x8*)(Plw + c * 80 + quad * 16);
#pragma unroll
                for (int dt = 0; dt < 4; ++dt)
                    O[t][dt] = mfma16(vA[dt], pB, O[t][dt]);
            }
        }
    };

    bf16x8 kA[2][2], vA[4], kB[2][2], vB[4], kC[2][2], vC[4];
    LK(0, kA, vA);
    if (1 < stmax) LK(1, kB, vB);
    for (int st = 0; st < stmax; st += 3) {
        if (st + 2 < stmax) LK(st + 2, kC, vC);
        CMP(st, kA, vA);
        if (st + 3 < stmax) LK(st + 3, kA, vA);
        if (st + 1 < stmax) CMP(st + 1, kB, vB);
        if (st + 4 < stmax) LK(st + 4, kB, vB);
        if (st + 2 < stmax) CMP(st + 2, kC, vC);
    }

#pragma unroll
    for (int t = 0; t < 4; ++t) {
        if (t < nt) {
            float v = sm[t];
            v += __shfl_xor(v, 16);
            v += __shfl_xor(v, 32);
            float iv = 1.0f / v;
            int q = (wave + 4 * t) * 16 + c;
            if (q < n) {
                size_t row = (size_t)(off + q) * 512 + h * 64;
#pragma unroll
                for (int dt = 0; dt < 4; ++dt) {
                    u16x4 o;
#pragma unroll
                    for (int r = 0; r < 4; ++r) o[r] = f2b(O[t][dt][r] * iv);
                    *(u16x4*)&ctx[row + dt * 16 + quad * 4] = o;
                }
            }
        }
    }
}

// -------- output projection + pad-row zeroing (merged, one launch) ----------
__global__ __launch_bounds__(512, 4) void k_out(
    const __hip_bfloat16* __restrict__ A,    // ctx [total][512]
    const __hip_bfloat16* __restrict__ W,    // [512][512]
    const float* __restrict__ bias,          // [512]
    const int* __restrict__ offs,            // [65]
    const int* __restrict__ agents,
    void* __restrict__ out,                  // [64][254][512] f32 or bf16
    const int* __restrict__ flag,
    int total, int MT)
{
    __shared__ __hip_bfloat16 As[2 * 128 * 64];
    __shared__ __hip_bfloat16 Ws[2 * 128 * 64];
    __shared__ int s_off[65];
    int l = blockIdx.x;
    int MTpad = ((MT + 7) >> 3) << 3;
    int tid = threadIdx.x;
    if (l >= 4 * MTpad) {
        // ---- zero-pad block for sample b ----
        int b = l - 4 * MTpad;
        int n = agents[b];
        int esz = flag[0] ? 4 : 2;
        long long base = ((long long)b * 254 + n) * 512 * esz;
        long long bytes = (long long)(254 - n) * 512 * esz;
        for (long long i = (long long)tid * 16; i < bytes; i += (long long)512 * 16)
            *(i32x4*)((char*)out + base + i) = (i32x4){0, 0, 0, 0};
        return;
    }
    int inner = l >> 3;
    int cb = inner & 3;
    int rb = (l & 7) + 8 * (inner >> 2);
    if (rb >= MT) return;
    int n0 = cb * 128;
    int m0 = rb * 128;
    if (tid < 65) s_off[tid] = offs[tid];
    f32x4 z = {0.f, 0.f, 0.f, 0.f};
    f32x4 acc[4][2] = {{z,z},{z,z},{z,z},{z,z}};
    gemm_core<512, false>(A, W, m0, n0, total, As, Ws, acc, tid);

    int f32m = flag[0];
    int lane = tid & 63, quad = lane >> 4, c = lane & 15;
    int wave = tid >> 6, wm = wave >> 2, wn = wave & 3;
    fl4 bv4[2];
#pragma unroll
    for (int j = 0; j < 2; ++j)
        bv4[j] = *(const fl4*)&bias[n0 + wn * 32 + j * 16 + quad * 4];
#pragma unroll
    for (int i = 0; i < 4; ++i) {
        int m = m0 + wm * 64 + i * 16 + c;
        if (m >= total) continue;
        int lo = bsearch_off(s_off, m);
        int os_ = m - s_off[lo];
        size_t rowb = ((size_t)(lo * 254 + os_)) * 512;
#pragma unroll
        for (int j = 0; j < 2; ++j) {
            int col0 = n0 + wn * 32 + j * 16 + quad * 4;
            if (f32m) {
                fl4 o;
#pragma unroll
                for (int r = 0; r < 4; ++r) o[r] = acc[i][j][r] + bv4[j][r];
                *(fl4*)&((float*)out)[rowb + col0] = o;
            } else {
                u16x4 o;
#pragma unroll
                for (int r = 0; r < 4; ++r) o[r] = f2b(acc[i][j][r] + bv4[j][r]);
                *(u16x4*)&((__hip_bfloat16*)out)[rowb + col0] = o;
            }
        }
    }
}

extern "C" void kernel_launch(void* const* d_in, const int* in_sizes, int n_in,
                              void* d_out, int out_size, void* d_ws, size_t ws_size,
                              hipStream_t stream) {
    const void* att_in = d_in[0];
    const void* w_in   = d_in[1];
    const void* b_in   = d_in[2];
    const void* w_out  = d_in[3];
    const void* b_out  = d_in[4];
    const int* agents  = (const int*)d_in[5];
    int total = in_sizes[0] / 512;

    char* p = (char*)d_ws;
    int* flag  = (int*)p;                 p += 256;
    int* offs  = (int*)p;                 p += 512;
    float* bfi = (float*)p;               p += 1536 * 4;
    float* bfo = (float*)p;               p += 512 * 4;
    __hip_bfloat16* WinBf  = (__hip_bfloat16*)p;  p += (size_t)1536 * 512 * 2;
    __hip_bfloat16* WoutBf = (__hip_bfloat16*)p;  p += (size_t)512 * 512 * 2;
    __hip_bfloat16* Abf    = (__hip_bfloat16*)p;  p += (size_t)total * 512 * 2;
    __hip_bfloat16* qP     = (__hip_bfloat16*)p;  p += (size_t)512 * 256 * 64 * 2;
    __hip_bfloat16* kP     = (__hip_bfloat16*)p;  p += (size_t)512 * 256 * 64 * 2;
    __hip_bfloat16* vT     = (__hip_bfloat16*)p;  p += (size_t)512 * 64 * 256 * 2;
    __hip_bfloat16* ctx    = (__hip_bfloat16*)p;  p += (size_t)total * 512 * 2;

    int nA = total * 512, nWi = 1536 * 512, nWo = 512 * 512;
    int ntot = nA + nWi + nWo;

    k_prep<<<1, 256, 0, stream>>>((const unsigned short*)att_in, b_in, b_out,
                                  agents, flag, offs, bfi, bfo);
    k_cast_all<<<(ntot / 4 + 255) / 256, 256, 0, stream>>>(
        att_in, (unsigned short*)Abf, nA,
        w_in,   (unsigned short*)WinBf, nWi,
        w_out,  (unsigned short*)WoutBf, nWo, flag);

    int MT = (total + 127) / 128;
    int MTpad = ((MT + 7) / 8) * 8;
    k_qkv<<<12 * MTpad, 512, 0, stream>>>(Abf, WinBf, bfi, offs, qP, kP, vT, total, MT);
    k_attn<<<512, 256, 0, stream>>>(qP, kP, vT, ctx, agents, offs);
    k_out<<<4 * MTpad + 64, 512, 0, stream>>>(ctx, WoutBf, bfo, offs, agents,
                                              d_out, flag, total, MT);
}